// Round 1
// baseline (185.181 us; speedup 1.0000x reference)
//
#include <hip/hip_runtime.h>
#include <math.h>

// Problem constants (fixed by the reference setup)
constexpr int BB = 64, LL = 512, DD = 768, SS = 30;
constexpr int NDOMc = 5, NGATEc = 3, PRED = 2;

// Output layout (flat float32, reference return order)
constexpr size_t O_DOM   = 0;                               // (B,5)
constexpr size_t O_SPP   = O_DOM   + (size_t)BB*NDOMc;      // (B,30) sigmoid
constexpr size_t O_GATE  = O_SPP   + (size_t)BB*SS;         // (B,30,3) softmax
constexpr size_t O_SPTR  = O_GATE  + (size_t)BB*SS*NGATEc;  // (B,30) passthrough
constexpr size_t O_SGATE = O_SPTR  + (size_t)BB*SS;         // (B,30) passthrough
constexpr size_t O_SPROB = O_SGATE + (size_t)BB*SS;         // (B,30,512)
constexpr size_t O_EPROB = O_SPROB + (size_t)BB*SS*LL;      // (B,30,512)

// Workspace layout (floats): WgW[30*768*3], bgW[96], then ints
constexpr int WS_WGW = 0;
constexpr int WS_BGW = SS*DD*NGATEc;        // 69120
constexpr int WS_INT = WS_BGW + 96;         // 69216 (float offset where ints start)

__device__ __forceinline__ float wred64(float v) {
    #pragma unroll
    for (int o = 32; o; o >>= 1) v += __shfl_xor(v, o);
    return v;
}

// ---------- Kernel A: per-batch small dots, passthrough, scan/compaction ----
__global__ __launch_bounds__(256) void kA(
    const float* __restrict__ cls, const float* __restrict__ Wdom,
    const float* __restrict__ bdom, const float* __restrict__ Wslot,
    const float* __restrict__ bslot, const int* __restrict__ sp,
    const int* __restrict__ sg, float* __restrict__ out,
    int* __restrict__ nptr, int* __restrict__ nsel,
    int* __restrict__ ptrpos, int* __restrict__ selpos)
{
    const int b = blockIdx.x;
    const int tid = threadIdx.x, lane = tid & 63, wid = tid >> 6;
    const float* c = cls + (size_t)b * DD;

    // 5 domain dots + 30 slot dots, one wave per task round-robin
    for (int t = wid; t < NDOMc + SS; t += 4) {
        float acc = 0.f;
        if (t < NDOMc) {
            for (int d = lane; d < DD; d += 64) acc += c[d] * Wdom[d*NDOMc + t];
        } else {
            const int j = t - NDOMc;
            for (int d = lane; d < DD; d += 64) acc += c[d] * Wslot[d*SS + j];
        }
        acc = wred64(acc);
        if (lane == 0) {
            if (t < NDOMc) out[O_DOM + (size_t)b*NDOMc + t] = acc + bdom[t];
            else {
                const int j = t - NDOMc;
                const float x = acc + bslot[j];
                out[O_SPP + (size_t)b*SS + j] = 1.f / (1.f + expf(-x));
            }
        }
    }
    // passthrough int -> float
    if (tid < SS) {
        out[O_SPTR  + (size_t)b*SS + tid] = (float)sp[b*SS + tid];
        out[O_SGATE + (size_t)b*SS + tid] = (float)sg[b*SS + tid];
    }
    // serial scan: ptr ranks and pmask compaction.
    // NOTE: gate_at_slot = slot_gate[b, clip(csum-1,0,M-1)] -> indexed by RANK.
    if (tid == 0) {
        int cp = 0, cs = 0;
        for (int i = 0; i < SS; ++i) {
            if (sp[b*SS + i] == 1) {
                const int rank = cp;            // csum-1 at this position
                ptrpos[b*SS + rank] = i;
                ++cp;
                if (sg[b*SS + rank] == PRED) { selpos[b*SS + cs] = i; ++cs; }
            }
        }
        nptr[b] = cp; nsel[b] = cs;
    }
}

// ---------- Kernel B: WgW[s,d,g] = sum_e Wg[s,d,e]*Wgate[e,g]; also bgW -----
__global__ __launch_bounds__(256) void kB(
    const float* __restrict__ Wg, const float* __restrict__ bg,
    const float* __restrict__ Wgate,
    float* __restrict__ WgW, float* __restrict__ bgW)
{
    const int lane = threadIdx.x & 63, wid = threadIdx.x >> 6;
    const int row = blockIdx.x * 4 + wid;       // row in [0, S*D + S)
    if (row >= SS*DD + SS) return;

    // per-lane W_gate values for this lane's e-range (same for every row)
    float wgt[3][4][3];
    #pragma unroll
    for (int j = 0; j < 3; ++j)
        #pragma unroll
        for (int cc = 0; cc < 4; ++cc) {
            const int e = j*256 + lane*4 + cc;
            #pragma unroll
            for (int g = 0; g < NGATEc; ++g) wgt[j][cc][g] = Wgate[e*NGATEc + g];
        }

    const float* src; float* dst;
    if (row < SS*DD) { src = Wg + (size_t)row * DD; dst = WgW + (size_t)row * 3; }
    else             { const int s = row - SS*DD; src = bg + (size_t)s * DD; dst = bgW + s*3; }

    const float4* s4 = (const float4*)src;
    float a0 = 0.f, a1 = 0.f, a2 = 0.f;
    #pragma unroll
    for (int j = 0; j < 3; ++j) {
        const float4 v = s4[j*64 + lane];
        a0 += v.x*wgt[j][0][0] + v.y*wgt[j][1][0] + v.z*wgt[j][2][0] + v.w*wgt[j][3][0];
        a1 += v.x*wgt[j][0][1] + v.y*wgt[j][1][1] + v.z*wgt[j][2][1] + v.w*wgt[j][3][1];
        a2 += v.x*wgt[j][0][2] + v.y*wgt[j][1][2] + v.z*wgt[j][2][2] + v.w*wgt[j][3][2];
    }
    a0 = wred64(a0); a1 = wred64(a1); a2 = wred64(a2);
    if (lane == 0) { dst[0] = a0; dst[1] = a1; dst[2] = a2; }
}

// ---------- Kernel C: slot_gate_prob ----------------------------------------
__global__ __launch_bounds__(256) void kC(
    const float* __restrict__ cls, const float* __restrict__ WgW,
    const float* __restrict__ bgW, const float* __restrict__ bgate,
    const int* __restrict__ nptr, const int* __restrict__ ptrpos,
    float* __restrict__ out)
{
    const int lane = threadIdx.x & 63, wid = threadIdx.x >> 6;
    const int idx = blockIdx.x * 4 + wid;       // b*SS + m
    if (idx >= BB*SS) return;
    const int b = idx / SS, m = idx % SS;

    float s0, s1, s2;
    if (m < nptr[b]) {
        const int s = ptrpos[b*SS + m];
        const float4* c4 = (const float4*)(cls + (size_t)b * DD);
        float a0 = 0.f, a1 = 0.f, a2 = 0.f;
        #pragma unroll
        for (int j = 0; j < 3; ++j) {
            const float4 v = c4[j*64 + lane];
            const float* wp = WgW + ((size_t)s*DD + j*256 + lane*4) * 3;
            a0 += v.x*wp[0] + v.y*wp[3] + v.z*wp[6] + v.w*wp[9];
            a1 += v.x*wp[1] + v.y*wp[4] + v.z*wp[7] + v.w*wp[10];
            a2 += v.x*wp[2] + v.y*wp[5] + v.z*wp[8] + v.w*wp[11];
        }
        a0 = wred64(a0); a1 = wred64(a1); a2 = wred64(a2);
        s0 = a0 + bgW[s*3+0] + bgate[0];
        s1 = a1 + bgW[s*3+1] + bgate[1];
        s2 = a2 + bgW[s*3+2] + bgate[2];
    } else {
        s0 = bgate[0]; s1 = bgate[1]; s2 = bgate[2];
    }
    if (lane == 0) {
        const float mx = fmaxf(s0, fmaxf(s1, s2));
        const float e0 = expf(s0 - mx), e1 = expf(s1 - mx), e2 = expf(s2 - mx);
        const float inv = 1.f / (e0 + e1 + e2);
        float* o = out + O_GATE + (size_t)idx * NGATEc;
        o[0] = e0*inv; o[1] = e1*inv; o[2] = e2*inv;
    }
}

// ---------- Kernel D: start/end scores + softmax over L ---------------------
__global__ __launch_bounds__(256) void kD(
    const float* __restrict__ H, const float* __restrict__ Ws,
    const float* __restrict__ We, const int* __restrict__ nsel,
    const int* __restrict__ selpos, float* __restrict__ out)
{
    const int blk = blockIdx.x;
    const int b = blk / SS, k = blk % SS;
    const int tid = threadIdx.x;
    float* outs = out + O_SPROB + (size_t)(b*SS + k) * LL;
    float* oute = out + O_EPROB + (size_t)(b*SS + k) * LL;

    const int ns = nsel[b];
    if (k >= ns) {                       // softmax(zeros) = 1/L exactly
        const float u = 1.0f / LL;
        for (int l = tid; l < LL; l += 256) { outs[l] = u; oute[l] = u; }
        return;
    }
    const int s = selpos[b*SS + k];
    const int lane = tid & 63, wid = tid >> 6;
    const int g = lane >> 4, m = lane & 15;   // 16-lane groups: 4 rows/wave/iter

    // weights in registers: this lane's 48-float slice of W_start/W_end[s]
    float4 wsr[12], wer[12];
    const float4* ws4 = (const float4*)(Ws + (size_t)s * DD);
    const float4* we4 = (const float4*)(We + (size_t)s * DD);
    #pragma unroll
    for (int j = 0; j < 12; ++j) { wsr[j] = ws4[j*16 + m]; wer[j] = we4[j*16 + m]; }

    __shared__ float ss_[LL], se_[LL];
    __shared__ float rmax[2][4], rsum[2][4];

    const float4* H4 = (const float4*)(H + (size_t)b * LL * DD);
    for (int it = 0; it < 32; ++it) {
        const int l = it*16 + wid*4 + g;
        const float4* h4 = H4 + (size_t)l * 192;
        float as = 0.f, ae = 0.f;
        #pragma unroll
        for (int j = 0; j < 12; ++j) {
            const float4 h = h4[j*16 + m];
            as += h.x*wsr[j].x + h.y*wsr[j].y + h.z*wsr[j].z + h.w*wsr[j].w;
            ae += h.x*wer[j].x + h.y*wer[j].y + h.z*wer[j].z + h.w*wer[j].w;
        }
        #pragma unroll
        for (int o = 8; o; o >>= 1) { as += __shfl_xor(as, o); ae += __shfl_xor(ae, o); }
        if (m == 0) { ss_[l] = as; se_[l] = ae; }   // b_start/b_end constant per row: softmax-invariant
    }
    __syncthreads();

    // block softmax over 512 for both rows
    float ms = fmaxf(ss_[tid], ss_[tid + 256]);
    float me = fmaxf(se_[tid], se_[tid + 256]);
    #pragma unroll
    for (int o = 32; o; o >>= 1) { ms = fmaxf(ms, __shfl_xor(ms, o)); me = fmaxf(me, __shfl_xor(me, o)); }
    if (lane == 0) { rmax[0][wid] = ms; rmax[1][wid] = me; }
    __syncthreads();
    ms = fmaxf(fmaxf(rmax[0][0], rmax[0][1]), fmaxf(rmax[0][2], rmax[0][3]));
    me = fmaxf(fmaxf(rmax[1][0], rmax[1][1]), fmaxf(rmax[1][2], rmax[1][3]));

    const float e0 = expf(ss_[tid] - ms), e1 = expf(ss_[tid + 256] - ms);
    const float f0 = expf(se_[tid] - me), f1 = expf(se_[tid + 256] - me);
    float sa = e0 + e1, sb = f0 + f1;
    #pragma unroll
    for (int o = 32; o; o >>= 1) { sa += __shfl_xor(sa, o); sb += __shfl_xor(sb, o); }
    if (lane == 0) { rsum[0][wid] = sa; rsum[1][wid] = sb; }
    __syncthreads();
    const float inva = 1.f / (rsum[0][0] + rsum[0][1] + rsum[0][2] + rsum[0][3]);
    const float invb = 1.f / (rsum[1][0] + rsum[1][1] + rsum[1][2] + rsum[1][3]);

    outs[tid] = e0 * inva; outs[tid + 256] = e1 * inva;
    oute[tid] = f0 * invb; oute[tid + 256] = f1 * invb;
}

extern "C" void kernel_launch(void* const* d_in, const int* in_sizes, int n_in,
                              void* d_out, int out_size, void* d_ws, size_t ws_size,
                              hipStream_t stream)
{
    const float* H      = (const float*)d_in[0];
    const float* cls    = (const float*)d_in[1];
    const float* Wdom   = (const float*)d_in[2];
    const float* bdom   = (const float*)d_in[3];
    const float* Wslot  = (const float*)d_in[4];
    const float* bslot  = (const float*)d_in[5];
    const float* Wg     = (const float*)d_in[6];
    const float* bg     = (const float*)d_in[7];
    const float* Wgate  = (const float*)d_in[8];
    const float* bgate  = (const float*)d_in[9];
    const float* Wstart = (const float*)d_in[10];
    // d_in[11] b_start: constant per softmax row -> unused
    const float* Wend   = (const float*)d_in[12];
    // d_in[13] b_end: unused (same reason)
    const int* sp = (const int*)d_in[14];
    const int* sg = (const int*)d_in[15];

    float* out = (float*)d_out;
    float* wsf = (float*)d_ws;
    float* WgW = wsf + WS_WGW;
    float* bgW = wsf + WS_BGW;
    int* ipart  = (int*)(wsf + WS_INT);
    int* nptr   = ipart;
    int* nsel   = ipart + 64;
    int* ptrpos = ipart + 128;
    int* selpos = ptrpos + BB*SS;

    kA<<<BB, 256, 0, stream>>>(cls, Wdom, bdom, Wslot, bslot, sp, sg, out,
                               nptr, nsel, ptrpos, selpos);
    kB<<<(SS*DD + SS + 3) / 4, 256, 0, stream>>>(Wg, bg, Wgate, WgW, bgW);
    kC<<<(BB*SS) / 4, 256, 0, stream>>>(cls, WgW, bgW, bgate, nptr, ptrpos, out);
    kD<<<BB*SS, 256, 0, stream>>>(H, Wstart, Wend, nsel, selpos, out);
}

// Round 2
// 98.108 us; speedup vs baseline: 1.8875x; 1.8875x over previous
//
#include <hip/hip_runtime.h>
#include <math.h>

// Problem constants (fixed by the reference setup)
constexpr int BB = 64, LL = 512, DD = 768, SS = 30;
constexpr int NDOMc = 5, NGATEc = 3, PRED = 2;

// Output layout (flat float32, reference return order)
constexpr size_t O_DOM   = 0;                               // (B,5)
constexpr size_t O_SPP   = O_DOM   + (size_t)BB*NDOMc;      // (B,30) sigmoid
constexpr size_t O_GATE  = O_SPP   + (size_t)BB*SS;         // (B,30,3) softmax
constexpr size_t O_SPTR  = O_GATE  + (size_t)BB*SS*NGATEc;  // (B,30) passthrough
constexpr size_t O_SGATE = O_SPTR  + (size_t)BB*SS;         // (B,30) passthrough
constexpr size_t O_SPROB = O_SGATE + (size_t)BB*SS;         // (B,30,512)
constexpr size_t O_EPROB = O_SPROB + (size_t)BB*SS*LL;      // (B,30,512)

// Workspace layout (floats): WgW[30*768*3], bgW[96], then ints
constexpr int WS_WGW = 0;
constexpr int WS_BGW = SS*DD*NGATEc;        // 69120
constexpr int WS_INT = WS_BGW + 96;         // 69216 (float offset where ints start)

__device__ __forceinline__ float wred64(float v) {
    #pragma unroll
    for (int o = 32; o; o >>= 1) v += __shfl_xor(v, o);
    return v;
}

// ---------- Kernel A: per-batch small dots, passthrough, scan/compaction ----
__global__ __launch_bounds__(256) void kA(
    const float* __restrict__ cls, const float* __restrict__ Wdom,
    const float* __restrict__ bdom, const float* __restrict__ Wslot,
    const float* __restrict__ bslot, const int* __restrict__ sp,
    const int* __restrict__ sg, float* __restrict__ out,
    int* __restrict__ nptr, int* __restrict__ nsel,
    int* __restrict__ ptrpos, int* __restrict__ selpos)
{
    const int b = blockIdx.x;
    const int tid = threadIdx.x, lane = tid & 63, wid = tid >> 6;
    const float* c = cls + (size_t)b * DD;

    for (int t = wid; t < NDOMc + SS; t += 4) {
        float acc = 0.f;
        if (t < NDOMc) {
            for (int d = lane; d < DD; d += 64) acc += c[d] * Wdom[d*NDOMc + t];
        } else {
            const int j = t - NDOMc;
            for (int d = lane; d < DD; d += 64) acc += c[d] * Wslot[d*SS + j];
        }
        acc = wred64(acc);
        if (lane == 0) {
            if (t < NDOMc) out[O_DOM + (size_t)b*NDOMc + t] = acc + bdom[t];
            else {
                const int j = t - NDOMc;
                const float x = acc + bslot[j];
                out[O_SPP + (size_t)b*SS + j] = 1.f / (1.f + expf(-x));
            }
        }
    }
    if (tid < SS) {
        out[O_SPTR  + (size_t)b*SS + tid] = (float)sp[b*SS + tid];
        out[O_SGATE + (size_t)b*SS + tid] = (float)sg[b*SS + tid];
    }
    // serial scan: ptr ranks and pmask compaction.
    // NOTE: gate_at_slot = slot_gate[b, clip(csum-1,0,M-1)] -> indexed by RANK.
    if (tid == 0) {
        int cp = 0, cs = 0;
        for (int i = 0; i < SS; ++i) {
            if (sp[b*SS + i] == 1) {
                const int rank = cp;            // csum-1 at this position
                ptrpos[b*SS + rank] = i;
                ++cp;
                if (sg[b*SS + rank] == PRED) { selpos[b*SS + cs] = i; ++cs; }
            }
        }
        nptr[b] = cp; nsel[b] = cs;
    }
}

// ---------- Kernel B: WgW[s,d,g] = sum_e Wg[s,d,e]*Wgate[e,g]; also bgW -----
__global__ __launch_bounds__(256) void kB(
    const float* __restrict__ Wg, const float* __restrict__ bg,
    const float* __restrict__ Wgate,
    float* __restrict__ WgW, float* __restrict__ bgW)
{
    const int lane = threadIdx.x & 63, wid = threadIdx.x >> 6;
    const int row = blockIdx.x * 4 + wid;       // row in [0, S*D + S)
    if (row >= SS*DD + SS) return;

    float wgt[3][4][3];
    #pragma unroll
    for (int j = 0; j < 3; ++j)
        #pragma unroll
        for (int cc = 0; cc < 4; ++cc) {
            const int e = j*256 + lane*4 + cc;
            #pragma unroll
            for (int g = 0; g < NGATEc; ++g) wgt[j][cc][g] = Wgate[e*NGATEc + g];
        }

    const float* src; float* dst;
    if (row < SS*DD) { src = Wg + (size_t)row * DD; dst = WgW + (size_t)row * 3; }
    else             { const int s = row - SS*DD; src = bg + (size_t)s * DD; dst = bgW + s*3; }

    const float4* s4 = (const float4*)src;
    float a0 = 0.f, a1 = 0.f, a2 = 0.f;
    #pragma unroll
    for (int j = 0; j < 3; ++j) {
        const float4 v = s4[j*64 + lane];
        a0 += v.x*wgt[j][0][0] + v.y*wgt[j][1][0] + v.z*wgt[j][2][0] + v.w*wgt[j][3][0];
        a1 += v.x*wgt[j][0][1] + v.y*wgt[j][1][1] + v.z*wgt[j][2][1] + v.w*wgt[j][3][1];
        a2 += v.x*wgt[j][0][2] + v.y*wgt[j][1][2] + v.z*wgt[j][2][2] + v.w*wgt[j][3][2];
    }
    a0 = wred64(a0); a1 = wred64(a1); a2 = wred64(a2);
    if (lane == 0) { dst[0] = a0; dst[1] = a1; dst[2] = a2; }
}

// ---------- Kernel C: slot_gate_prob ----------------------------------------
__global__ __launch_bounds__(256) void kC(
    const float* __restrict__ cls, const float* __restrict__ WgW,
    const float* __restrict__ bgW, const float* __restrict__ bgate,
    const int* __restrict__ nptr, const int* __restrict__ ptrpos,
    float* __restrict__ out)
{
    const int lane = threadIdx.x & 63, wid = threadIdx.x >> 6;
    const int idx = blockIdx.x * 4 + wid;       // b*SS + m
    if (idx >= BB*SS) return;
    const int b = idx / SS, m = idx % SS;

    float s0, s1, s2;
    if (m < nptr[b]) {
        const int s = ptrpos[b*SS + m];
        const float4* c4 = (const float4*)(cls + (size_t)b * DD);
        float a0 = 0.f, a1 = 0.f, a2 = 0.f;
        #pragma unroll
        for (int j = 0; j < 3; ++j) {
            const float4 v = c4[j*64 + lane];
            const float* wp = WgW + ((size_t)s*DD + j*256 + lane*4) * 3;
            a0 += v.x*wp[0] + v.y*wp[3] + v.z*wp[6] + v.w*wp[9];
            a1 += v.x*wp[1] + v.y*wp[4] + v.z*wp[7] + v.w*wp[10];
            a2 += v.x*wp[2] + v.y*wp[5] + v.z*wp[8] + v.w*wp[11];
        }
        a0 = wred64(a0); a1 = wred64(a1); a2 = wred64(a2);
        s0 = a0 + bgW[s*3+0] + bgate[0];
        s1 = a1 + bgW[s*3+1] + bgate[1];
        s2 = a2 + bgW[s*3+2] + bgate[2];
    } else {
        s0 = bgate[0]; s1 = bgate[1]; s2 = bgate[2];
    }
    if (lane == 0) {
        const float mx = fmaxf(s0, fmaxf(s1, s2));
        const float e0 = expf(s0 - mx), e1 = expf(s1 - mx), e2 = expf(s2 - mx);
        const float inv = 1.f / (e0 + e1 + e2);
        float* o = out + O_GATE + (size_t)idx * NGATEc;
        o[0] = e0*inv; o[1] = e1*inv; o[2] = e2*inv;
    }
}

// ---------- Kernel D1: scores. H read ONCE; raw scores -> output regions ----
// grid 64 batches x 32 chunks; 16 rows/block; each 16-lane group owns a row.
__global__ __launch_bounds__(256) void kD1(
    const float* __restrict__ H, const float* __restrict__ Ws,
    const float* __restrict__ We, const int* __restrict__ nsel,
    const int* __restrict__ selpos, float* __restrict__ out)
{
    const int b = blockIdx.x >> 5;
    const int chunk = blockIdx.x & 31;
    const int ns = nsel[b];
    if (ns == 0) return;

    const int tid = threadIdx.x;
    const int grp = tid >> 4, m = tid & 15;
    const int l = chunk * 16 + grp;

    // H row slice in registers (48 floats/lane)
    const float4* h4 = (const float4*)(H + ((size_t)b * LL + l) * DD);
    float4 hr[12];
    #pragma unroll
    for (int j = 0; j < 12; ++j) hr[j] = h4[j*16 + m];

    for (int k = 0; k < ns; ++k) {
        const int s = selpos[b*SS + k];
        const float4* ws4 = (const float4*)(Ws + (size_t)s * DD);
        const float4* we4 = (const float4*)(We + (size_t)s * DD);
        float as = 0.f, ae = 0.f;
        #pragma unroll
        for (int j = 0; j < 12; ++j) {
            const float4 w = ws4[j*16 + m];
            const float v = 0.f; (void)v;
            as += hr[j].x*w.x + hr[j].y*w.y + hr[j].z*w.z + hr[j].w*w.w;
            const float4 u = we4[j*16 + m];
            ae += hr[j].x*u.x + hr[j].y*u.y + hr[j].z*u.z + hr[j].w*u.w;
        }
        #pragma unroll
        for (int o = 8; o; o >>= 1) { as += __shfl_xor(as, o); ae += __shfl_xor(ae, o); }
        if (m == 0) {
            out[O_SPROB + (size_t)(b*SS + k) * LL + l] = as;
            out[O_EPROB + (size_t)(b*SS + k) * LL + l] = ae;
        }
    }
}

// ---------- Kernel E: softmax in place over L=512 ---------------------------
__global__ __launch_bounds__(256) void kE(
    const int* __restrict__ nsel, float* __restrict__ out)
{
    const int idx = blockIdx.x;             // b*SS + k
    const int b = idx / SS, k = idx % SS;
    const int tid = threadIdx.x;
    float* outs = out + O_SPROB + (size_t)idx * LL;
    float* oute = out + O_EPROB + (size_t)idx * LL;

    if (k >= nsel[b]) {                     // softmax(zeros) = 1/L exactly
        const float u = 1.0f / LL;
        outs[tid] = u; outs[tid + 256] = u;
        oute[tid] = u; oute[tid + 256] = u;
        return;
    }
    const int lane = tid & 63, wid = tid >> 6;
    __shared__ float rmax[2][4], rsum[2][4];

    const float s0 = outs[tid], s1 = outs[tid + 256];
    const float t0 = oute[tid], t1 = oute[tid + 256];

    float ms = fmaxf(s0, s1), me = fmaxf(t0, t1);
    #pragma unroll
    for (int o = 32; o; o >>= 1) { ms = fmaxf(ms, __shfl_xor(ms, o)); me = fmaxf(me, __shfl_xor(me, o)); }
    if (lane == 0) { rmax[0][wid] = ms; rmax[1][wid] = me; }
    __syncthreads();
    ms = fmaxf(fmaxf(rmax[0][0], rmax[0][1]), fmaxf(rmax[0][2], rmax[0][3]));
    me = fmaxf(fmaxf(rmax[1][0], rmax[1][1]), fmaxf(rmax[1][2], rmax[1][3]));

    const float e0 = expf(s0 - ms), e1 = expf(s1 - ms);
    const float f0 = expf(t0 - me), f1 = expf(t1 - me);
    float sa = e0 + e1, sb = f0 + f1;
    #pragma unroll
    for (int o = 32; o; o >>= 1) { sa += __shfl_xor(sa, o); sb += __shfl_xor(sb, o); }
    if (lane == 0) { rsum[0][wid] = sa; rsum[1][wid] = sb; }
    __syncthreads();
    const float inva = 1.f / (rsum[0][0] + rsum[0][1] + rsum[0][2] + rsum[0][3]);
    const float invb = 1.f / (rsum[1][0] + rsum[1][1] + rsum[1][2] + rsum[1][3]);

    outs[tid] = e0 * inva; outs[tid + 256] = e1 * inva;
    oute[tid] = f0 * invb; oute[tid + 256] = f1 * invb;
}

extern "C" void kernel_launch(void* const* d_in, const int* in_sizes, int n_in,
                              void* d_out, int out_size, void* d_ws, size_t ws_size,
                              hipStream_t stream)
{
    const float* H      = (const float*)d_in[0];
    const float* cls    = (const float*)d_in[1];
    const float* Wdom   = (const float*)d_in[2];
    const float* bdom   = (const float*)d_in[3];
    const float* Wslot  = (const float*)d_in[4];
    const float* bslot  = (const float*)d_in[5];
    const float* Wg     = (const float*)d_in[6];
    const float* bg     = (const float*)d_in[7];
    const float* Wgate  = (const float*)d_in[8];
    const float* bgate  = (const float*)d_in[9];
    const float* Wstart = (const float*)d_in[10];
    // d_in[11] b_start: constant per softmax row -> softmax-invariant, unused
    const float* Wend   = (const float*)d_in[12];
    // d_in[13] b_end: unused (same reason)
    const int* sp = (const int*)d_in[14];
    const int* sg = (const int*)d_in[15];

    float* out = (float*)d_out;
    float* wsf = (float*)d_ws;
    float* WgW = wsf + WS_WGW;
    float* bgW = wsf + WS_BGW;
    int* ipart  = (int*)(wsf + WS_INT);
    int* nptr   = ipart;
    int* nsel   = ipart + 64;
    int* ptrpos = ipart + 128;
    int* selpos = ptrpos + BB*SS;

    kA<<<BB, 256, 0, stream>>>(cls, Wdom, bdom, Wslot, bslot, sp, sg, out,
                               nptr, nsel, ptrpos, selpos);
    kB<<<(SS*DD + SS + 3) / 4, 256, 0, stream>>>(Wg, bg, Wgate, WgW, bgW);
    kD1<<<BB * 32, 256, 0, stream>>>(H, Wstart, Wend, nsel, selpos, out);
    kC<<<(BB*SS) / 4, 256, 0, stream>>>(cls, WgW, bgW, bgate, nptr, ptrpos, out);
    kE<<<BB * SS, 256, 0, stream>>>(nsel, out);
}

// Round 3
// 93.661 us; speedup vs baseline: 1.9771x; 1.0475x over previous
//
#include <hip/hip_runtime.h>
#include <math.h>

// Problem constants (fixed by the reference setup)
constexpr int BB = 64, LL = 512, DD = 768, SS = 30;
constexpr int NDOMc = 5, NGATEc = 3, PRED = 2;

// Output layout (flat float32, reference return order)
constexpr size_t O_DOM   = 0;                               // (B,5)
constexpr size_t O_SPP   = O_DOM   + (size_t)BB*NDOMc;      // (B,30) sigmoid
constexpr size_t O_GATE  = O_SPP   + (size_t)BB*SS;         // (B,30,3) softmax
constexpr size_t O_SPTR  = O_GATE  + (size_t)BB*SS*NGATEc;  // (B,30) passthrough
constexpr size_t O_SGATE = O_SPTR  + (size_t)BB*SS;         // (B,30) passthrough
constexpr size_t O_SPROB = O_SGATE + (size_t)BB*SS;         // (B,30,512)
constexpr size_t O_EPROB = O_SPROB + (size_t)BB*SS*LL;      // (B,30,512)

// Workspace layout (floats): WgW[30*768*3], bgW[96], then ints
constexpr int WS_WGW = 0;
constexpr int WS_BGW = SS*DD*NGATEc;        // 69120
constexpr int WS_INT = WS_BGW + 96;         // 69216 (float offset where ints start)

constexpr int KB_ROWS = SS*DD + SS;         // 23070 (even split at 23040 boundary)

__device__ __forceinline__ float wred64(float v) {
    #pragma unroll
    for (int o = 32; o; o >>= 1) v += __shfl_xor(v, o);
    return v;
}

// ---------- Kernel A: per-batch small dots, passthrough, scan/compaction ----
__global__ __launch_bounds__(256) void kA(
    const float* __restrict__ cls, const float* __restrict__ Wdom,
    const float* __restrict__ bdom, const float* __restrict__ Wslot,
    const float* __restrict__ bslot, const int* __restrict__ sp,
    const int* __restrict__ sg, float* __restrict__ out,
    int* __restrict__ nptr, int* __restrict__ nsel,
    int* __restrict__ ptrpos, int* __restrict__ selpos)
{
    const int b = blockIdx.x;
    const int tid = threadIdx.x, lane = tid & 63, wid = tid >> 6;
    const float* c = cls + (size_t)b * DD;

    for (int t = wid; t < NDOMc + SS; t += 4) {
        float acc = 0.f;
        if (t < NDOMc) {
            for (int d = lane; d < DD; d += 64) acc += c[d] * Wdom[d*NDOMc + t];
        } else {
            const int j = t - NDOMc;
            for (int d = lane; d < DD; d += 64) acc += c[d] * Wslot[d*SS + j];
        }
        acc = wred64(acc);
        if (lane == 0) {
            if (t < NDOMc) out[O_DOM + (size_t)b*NDOMc + t] = acc + bdom[t];
            else {
                const int j = t - NDOMc;
                const float x = acc + bslot[j];
                out[O_SPP + (size_t)b*SS + j] = 1.f / (1.f + expf(-x));
            }
        }
    }
    if (tid < SS) {
        out[O_SPTR  + (size_t)b*SS + tid] = (float)sp[b*SS + tid];
        out[O_SGATE + (size_t)b*SS + tid] = (float)sg[b*SS + tid];
    }
    // serial scan: ptr ranks and pmask compaction.
    // NOTE: gate_at_slot = slot_gate[b, clip(csum-1,0,M-1)] -> indexed by RANK.
    if (tid == 0) {
        int cp = 0, cs = 0;
        for (int i = 0; i < SS; ++i) {
            if (sp[b*SS + i] == 1) {
                const int rank = cp;            // csum-1 at this position
                ptrpos[b*SS + rank] = i;
                ++cp;
                if (sg[b*SS + rank] == PRED) { selpos[b*SS + cs] = i; ++cs; }
            }
        }
        nptr[b] = cp; nsel[b] = cs;
    }
}

// ---------- Kernel B: WgW[row,g] = sum_e src[row,e]*Wgate[e,g]; 2 rows/wave --
__global__ __launch_bounds__(256) void kB(
    const float* __restrict__ Wg, const float* __restrict__ bg,
    const float* __restrict__ Wgate,
    float* __restrict__ WgW, float* __restrict__ bgW)
{
    const int lane = threadIdx.x & 63, wid = threadIdx.x >> 6;
    const int r0 = (blockIdx.x * 4 + wid) * 2;      // rows r0, r0+1
    if (r0 >= KB_ROWS) return;

    // per-lane W_gate values for this lane's e-range (shared by both rows)
    float wgt[3][4][3];
    #pragma unroll
    for (int j = 0; j < 3; ++j)
        #pragma unroll
        for (int cc = 0; cc < 4; ++cc) {
            const int e = j*256 + lane*4 + cc;
            #pragma unroll
            for (int g = 0; g < NGATEc; ++g) wgt[j][cc][g] = Wgate[e*NGATEc + g];
        }

    const float* src0 = (r0 < SS*DD) ? Wg + (size_t)r0*DD : bg + (size_t)(r0 - SS*DD)*DD;
    const int r1 = r0 + 1;
    const float* src1 = (r1 < SS*DD) ? Wg + (size_t)r1*DD : bg + (size_t)(r1 - SS*DD)*DD;
    float* dst0 = (r0 < SS*DD) ? WgW + (size_t)r0*3 : bgW + (r0 - SS*DD)*3;
    float* dst1 = (r1 < SS*DD) ? WgW + (size_t)r1*3 : bgW + (r1 - SS*DD)*3;

    const float4* s40 = (const float4*)src0;
    const float4* s41 = (const float4*)src1;
    float a0=0,a1=0,a2=0, c0=0,c1=0,c2=0;
    #pragma unroll
    for (int j = 0; j < 3; ++j) {
        const float4 v = s40[j*64 + lane];
        const float4 w = s41[j*64 + lane];
        a0 += v.x*wgt[j][0][0] + v.y*wgt[j][1][0] + v.z*wgt[j][2][0] + v.w*wgt[j][3][0];
        a1 += v.x*wgt[j][0][1] + v.y*wgt[j][1][1] + v.z*wgt[j][2][1] + v.w*wgt[j][3][1];
        a2 += v.x*wgt[j][0][2] + v.y*wgt[j][1][2] + v.z*wgt[j][2][2] + v.w*wgt[j][3][2];
        c0 += w.x*wgt[j][0][0] + w.y*wgt[j][1][0] + w.z*wgt[j][2][0] + w.w*wgt[j][3][0];
        c1 += w.x*wgt[j][0][1] + w.y*wgt[j][1][1] + w.z*wgt[j][2][1] + w.w*wgt[j][3][1];
        c2 += w.x*wgt[j][0][2] + w.y*wgt[j][1][2] + w.z*wgt[j][2][2] + w.w*wgt[j][3][2];
    }
    a0 = wred64(a0); a1 = wred64(a1); a2 = wred64(a2);
    c0 = wred64(c0); c1 = wred64(c1); c2 = wred64(c2);
    if (lane == 0) {
        dst0[0] = a0; dst0[1] = a1; dst0[2] = a2;
        dst1[0] = c0; dst1[1] = c1; dst1[2] = c2;
    }
}

// ---------- Kernel C: slot_gate_prob ----------------------------------------
__global__ __launch_bounds__(256) void kC(
    const float* __restrict__ cls, const float* __restrict__ WgW,
    const float* __restrict__ bgW, const float* __restrict__ bgate,
    const int* __restrict__ nptr, const int* __restrict__ ptrpos,
    float* __restrict__ out)
{
    const int lane = threadIdx.x & 63, wid = threadIdx.x >> 6;
    const int idx = blockIdx.x * 4 + wid;       // b*SS + m
    if (idx >= BB*SS) return;
    const int b = idx / SS, m = idx % SS;

    float s0, s1, s2;
    if (m < nptr[b]) {
        const int s = ptrpos[b*SS + m];
        const float4* c4 = (const float4*)(cls + (size_t)b * DD);
        float a0 = 0.f, a1 = 0.f, a2 = 0.f;
        #pragma unroll
        for (int j = 0; j < 3; ++j) {
            const float4 v = c4[j*64 + lane];
            const float* wp = WgW + ((size_t)s*DD + j*256 + lane*4) * 3;
            a0 += v.x*wp[0] + v.y*wp[3] + v.z*wp[6] + v.w*wp[9];
            a1 += v.x*wp[1] + v.y*wp[4] + v.z*wp[7] + v.w*wp[10];
            a2 += v.x*wp[2] + v.y*wp[5] + v.z*wp[8] + v.w*wp[11];
        }
        a0 = wred64(a0); a1 = wred64(a1); a2 = wred64(a2);
        s0 = a0 + bgW[s*3+0] + bgate[0];
        s1 = a1 + bgW[s*3+1] + bgate[1];
        s2 = a2 + bgW[s*3+2] + bgate[2];
    } else {
        s0 = bgate[0]; s1 = bgate[1]; s2 = bgate[2];
    }
    if (lane == 0) {
        const float mx = fmaxf(s0, fmaxf(s1, s2));
        const float e0 = expf(s0 - mx), e1 = expf(s1 - mx), e2 = expf(s2 - mx);
        const float inv = 1.f / (e0 + e1 + e2);
        float* o = out + O_GATE + (size_t)idx * NGATEc;
        o[0] = e0*inv; o[1] = e1*inv; o[2] = e2*inv;
    }
}

// ---------- Kernel D1: scores. H read ONCE; 2 rows per 16-lane group --------
// grid: 16 chunks x 64 batches, b = bid & 63 (batch-interleaved for balance).
__global__ __launch_bounds__(256, 2) void kD1(
    const float* __restrict__ H, const float* __restrict__ Ws,
    const float* __restrict__ We, const int* __restrict__ nsel,
    const int* __restrict__ selpos, float* __restrict__ out)
{
    const int b = blockIdx.x & 63;
    const int chunk = blockIdx.x >> 6;          // 0..15
    const int ns = nsel[b];
    if (ns == 0) return;

    const int tid = threadIdx.x;
    const int grp = tid >> 4, m = tid & 15;     // 16-lane groups
    const int l0 = chunk * 32 + grp;            // rows l0 and l0+16
    const int l1 = l0 + 16;

    // H row slices in registers (2 x 48 floats/lane)
    const float4* h40 = (const float4*)(H + ((size_t)b * LL + l0) * DD);
    const float4* h41 = (const float4*)(H + ((size_t)b * LL + l1) * DD);
    float4 hr0[12], hr1[12];
    #pragma unroll
    for (int j = 0; j < 12; ++j) hr0[j] = h40[j*16 + m];
    #pragma unroll
    for (int j = 0; j < 12; ++j) hr1[j] = h41[j*16 + m];

    for (int k = 0; k < ns; ++k) {
        const int s = selpos[b*SS + k];
        const float4* ws4 = (const float4*)(Ws + (size_t)s * DD);
        const float4* we4 = (const float4*)(We + (size_t)s * DD);
        float as0=0.f, as1=0.f, ae0=0.f, ae1=0.f;
        #pragma unroll
        for (int j = 0; j < 12; ++j) {
            const float4 w = ws4[j*16 + m];
            as0 += hr0[j].x*w.x + hr0[j].y*w.y + hr0[j].z*w.z + hr0[j].w*w.w;
            as1 += hr1[j].x*w.x + hr1[j].y*w.y + hr1[j].z*w.z + hr1[j].w*w.w;
        }
        #pragma unroll
        for (int j = 0; j < 12; ++j) {
            const float4 u = we4[j*16 + m];
            ae0 += hr0[j].x*u.x + hr0[j].y*u.y + hr0[j].z*u.z + hr0[j].w*u.w;
            ae1 += hr1[j].x*u.x + hr1[j].y*u.y + hr1[j].z*u.z + hr1[j].w*u.w;
        }
        #pragma unroll
        for (int o = 8; o; o >>= 1) {
            as0 += __shfl_xor(as0, o); as1 += __shfl_xor(as1, o);
            ae0 += __shfl_xor(ae0, o); ae1 += __shfl_xor(ae1, o);
        }
        if (m == 0) {
            float* po = out + O_SPROB + (size_t)(b*SS + k) * LL;
            float* pe = out + O_EPROB + (size_t)(b*SS + k) * LL;
            po[l0] = as0; po[l1] = as1;
            pe[l0] = ae0; pe[l1] = ae1;
        }
    }
}

// ---------- Kernel E: softmax in place over L=512 ---------------------------
__global__ __launch_bounds__(256) void kE(
    const int* __restrict__ nsel, float* __restrict__ out)
{
    const int idx = blockIdx.x;             // b*SS + k
    const int b = idx / SS, k = idx % SS;
    const int tid = threadIdx.x;
    float* outs = out + O_SPROB + (size_t)idx * LL;
    float* oute = out + O_EPROB + (size_t)idx * LL;

    if (k >= nsel[b]) {                     // softmax(zeros) = 1/L exactly
        const float u = 1.0f / LL;
        outs[tid] = u; outs[tid + 256] = u;
        oute[tid] = u; oute[tid + 256] = u;
        return;
    }
    const int lane = tid & 63, wid = tid >> 6;
    __shared__ float rmax[2][4], rsum[2][4];

    const float s0 = outs[tid], s1 = outs[tid + 256];
    const float t0 = oute[tid], t1 = oute[tid + 256];

    float ms = fmaxf(s0, s1), me = fmaxf(t0, t1);
    #pragma unroll
    for (int o = 32; o; o >>= 1) { ms = fmaxf(ms, __shfl_xor(ms, o)); me = fmaxf(me, __shfl_xor(me, o)); }
    if (lane == 0) { rmax[0][wid] = ms; rmax[1][wid] = me; }
    __syncthreads();
    ms = fmaxf(fmaxf(rmax[0][0], rmax[0][1]), fmaxf(rmax[0][2], rmax[0][3]));
    me = fmaxf(fmaxf(rmax[1][0], rmax[1][1]), fmaxf(rmax[1][2], rmax[1][3]));

    const float e0 = expf(s0 - ms), e1 = expf(s1 - ms);
    const float f0 = expf(t0 - me), f1 = expf(t1 - me);
    float sa = e0 + e1, sb = f0 + f1;
    #pragma unroll
    for (int o = 32; o; o >>= 1) { sa += __shfl_xor(sa, o); sb += __shfl_xor(sb, o); }
    if (lane == 0) { rsum[0][wid] = sa; rsum[1][wid] = sb; }
    __syncthreads();
    const float inva = 1.f / (rsum[0][0] + rsum[0][1] + rsum[0][2] + rsum[0][3]);
    const float invb = 1.f / (rsum[1][0] + rsum[1][1] + rsum[1][2] + rsum[1][3]);

    outs[tid] = e0 * inva; outs[tid + 256] = e1 * inva;
    oute[tid] = f0 * invb; oute[tid + 256] = f1 * invb;
}

extern "C" void kernel_launch(void* const* d_in, const int* in_sizes, int n_in,
                              void* d_out, int out_size, void* d_ws, size_t ws_size,
                              hipStream_t stream)
{
    const float* H      = (const float*)d_in[0];
    const float* cls    = (const float*)d_in[1];
    const float* Wdom   = (const float*)d_in[2];
    const float* bdom   = (const float*)d_in[3];
    const float* Wslot  = (const float*)d_in[4];
    const float* bslot  = (const float*)d_in[5];
    const float* Wg     = (const float*)d_in[6];
    const float* bg     = (const float*)d_in[7];
    const float* Wgate  = (const float*)d_in[8];
    const float* bgate  = (const float*)d_in[9];
    const float* Wstart = (const float*)d_in[10];
    // d_in[11] b_start: constant per softmax row -> softmax-invariant, unused
    const float* Wend   = (const float*)d_in[12];
    // d_in[13] b_end: unused (same reason)
    const int* sp = (const int*)d_in[14];
    const int* sg = (const int*)d_in[15];

    float* out = (float*)d_out;
    float* wsf = (float*)d_ws;
    float* WgW = wsf + WS_WGW;
    float* bgW = wsf + WS_BGW;
    int* ipart  = (int*)(wsf + WS_INT);
    int* nptr   = ipart;
    int* nsel   = ipart + 64;
    int* ptrpos = ipart + 128;
    int* selpos = ptrpos + BB*SS;

    kA<<<BB, 256, 0, stream>>>(cls, Wdom, bdom, Wslot, bslot, sp, sg, out,
                               nptr, nsel, ptrpos, selpos);
    kB<<<(KB_ROWS/2 + 3) / 4, 256, 0, stream>>>(Wg, bg, Wgate, WgW, bgW);
    kD1<<<BB * 16, 256, 0, stream>>>(H, Wstart, Wend, nsel, selpos, out);
    kC<<<(BB*SS) / 4, 256, 0, stream>>>(cls, WgW, bgW, bgate, nptr, ptrpos, out);
    kE<<<BB * SS, 256, 0, stream>>>(nsel, out);
}